// Round 1
// baseline (90.907 us; speedup 1.0000x reference)
//
#include <hip/hip_runtime.h>
#include <math.h>

#define BB   1024   // batch rows
#define FF   1024   // real features (f=1024 is the zero-bias row)
#define NOUT 512    // 256 erosion cols | 256 dilation cols
#define NW   256    // cols per weight matrix
#define BT   128    // rows per block tile
#define NT   64     // cols per block tile
#define KT   32     // f per LDS chunk

// 256 threads: cg = tid&7 (8 col groups x 8 cols), rg = tid>>3 (32 row groups x 4 rows)
// Unified max-plus: erosion computed as -max_f((-x)+e), dilation as max_f(x+d).
__global__ __launch_bounds__(256, 2) void trop_main(
    const float* __restrict__ x,
    const float* __restrict__ dil,
    const float* __restrict__ ero,
    float* __restrict__ dst,   // partials base (ws) or d_out when direct
    int ks, int ch, int direct)
{
    const int bx = blockIdx.x;   // 0..7 col tile (0..3 erosion, 4..7 dilation)
    const int by = blockIdx.y;   // 0..7 row tile
    const int bz = blockIdx.z;   // 0..ks-1 K split
    const bool is_ero = (bx < (NW / NT));
    const float* __restrict__ w = is_ero ? ero : dil;
    const int c0w = is_ero ? bx * NT : bx * NT - NW;   // col offset inside weight matrix
    const int r0 = by * BT;
    const float sgn = is_ero ? -1.0f : 1.0f;

    __shared__ float lds_x[KT][BT];   // x^T (sign-applied)
    __shared__ float lds_w[KT][NT];

    const int tid = threadIdx.x;
    const int cg = tid & 7;
    const int rg = tid >> 3;

    float acc[4][8];
#pragma unroll
    for (int i = 0; i < 4; ++i)
#pragma unroll
        for (int j = 0; j < 8; ++j) acc[i][j] = -INFINITY;

    const int fstart = bz * ch;
    const int nchunk = ch / KT;

    for (int kc = 0; kc < nchunk; ++kc) {
        const int fb = fstart + kc * KT;

        // ---- stage x^T (128 rows x 32 f), sign applied ----
#pragma unroll
        for (int it = 0; it < 4; ++it) {
            const int tt = tid + it * 256;
            const int r = tt & 127;
            const int g = tt >> 7;                 // 0..7 -> f group of 4
            const float4 v = *(const float4*)(x + (size_t)(r0 + r) * FF + fb + g * 4);
            lds_x[g * 4 + 0][r] = sgn * v.x;
            lds_x[g * 4 + 1][r] = sgn * v.y;
            lds_x[g * 4 + 2][r] = sgn * v.z;
            lds_x[g * 4 + 3][r] = sgn * v.w;
        }
        // ---- stage w (32 f x 64 cols), natural layout ----
#pragma unroll
        for (int it = 0; it < 2; ++it) {
            const int tt = tid + it * 256;
            const int f = tt >> 4;                 // 0..31
            const int c4 = tt & 15;                // 0..15
            *(float4*)&lds_w[f][c4 * 4] =
                *(const float4*)(w + (size_t)(fb + f) * NW + c0w + c4 * 4);
        }
        __syncthreads();

        // ---- max-plus inner loop, K-unrolled by 2 for v_max3 fusion ----
#pragma unroll
        for (int ff = 0; ff < KT; ff += 2) {
            const float4 x0 = *(const float4*)&lds_x[ff][rg << 2];
            const float4 x1 = *(const float4*)&lds_x[ff + 1][rg << 2];
            const float4 wa0 = *(const float4*)&lds_w[ff][cg << 3];
            const float4 wb0 = *(const float4*)&lds_w[ff][(cg << 3) + 4];
            const float4 wa1 = *(const float4*)&lds_w[ff + 1][cg << 3];
            const float4 wb1 = *(const float4*)&lds_w[ff + 1][(cg << 3) + 4];
            const float xr0[4] = {x0.x, x0.y, x0.z, x0.w};
            const float xr1[4] = {x1.x, x1.y, x1.z, x1.w};
            const float wc0[8] = {wa0.x, wa0.y, wa0.z, wa0.w, wb0.x, wb0.y, wb0.z, wb0.w};
            const float wc1[8] = {wa1.x, wa1.y, wa1.z, wa1.w, wb1.x, wb1.y, wb1.z, wb1.w};
#pragma unroll
            for (int i = 0; i < 4; ++i)
#pragma unroll
                for (int j = 0; j < 8; ++j) {
                    acc[i][j] = fmaxf(acc[i][j],
                                      fmaxf(xr0[i] + wc0[j], xr1[i] + wc1[j]));
                }
        }
        __syncthreads();
    }

    // ---- bias row f=1024 (x contribution is 0; (-0)+e = e, 0+d = d) ----
    if (bz == ks - 1) {
        const float4 ba = *(const float4*)(w + (size_t)FF * NW + c0w + (cg << 3));
        const float4 bb = *(const float4*)(w + (size_t)FF * NW + c0w + (cg << 3) + 4);
        const float bc[8] = {ba.x, ba.y, ba.z, ba.w, bb.x, bb.y, bb.z, bb.w};
#pragma unroll
        for (int i = 0; i < 4; ++i)
#pragma unroll
            for (int j = 0; j < 8; ++j) acc[i][j] = fmaxf(acc[i][j], bc[j]);
    }

    // ---- store (undo sign for erosion) ----
    float* base = direct ? dst : dst + (size_t)bz * (BB * NOUT);
    const int cglob = bx * NT + (cg << 3);
#pragma unroll
    for (int i = 0; i < 4; ++i) {
        const int row = r0 + (rg << 2) + i;
        float4 v0, v1;
        v0.x = sgn * acc[i][0]; v0.y = sgn * acc[i][1];
        v0.z = sgn * acc[i][2]; v0.w = sgn * acc[i][3];
        v1.x = sgn * acc[i][4]; v1.y = sgn * acc[i][5];
        v1.z = sgn * acc[i][6]; v1.w = sgn * acc[i][7];
        *(float4*)(base + (size_t)row * NOUT + cglob) = v0;
        *(float4*)(base + (size_t)row * NOUT + cglob + 4) = v1;
    }
}

// combine K-split partials: min for erosion cols (<256), max for dilation cols
__global__ __launch_bounds__(256) void trop_combine(
    const float* __restrict__ ws, float* __restrict__ out, int ks)
{
    const int i4 = blockIdx.x * blockDim.x + threadIdx.x;   // float4 index
    const int col4 = (i4 << 2) & (NOUT - 1);
    const bool ero = col4 < NW;
    const int stride4 = BB * NOUT / 4;
    float4 v = ((const float4*)ws)[i4];
    for (int z = 1; z < ks; ++z) {
        const float4 u = ((const float4*)ws)[(size_t)z * stride4 + i4];
        if (ero) {
            v.x = fminf(v.x, u.x); v.y = fminf(v.y, u.y);
            v.z = fminf(v.z, u.z); v.w = fminf(v.w, u.w);
        } else {
            v.x = fmaxf(v.x, u.x); v.y = fmaxf(v.y, u.y);
            v.z = fmaxf(v.z, u.z); v.w = fmaxf(v.w, u.w);
        }
    }
    ((float4*)out)[i4] = v;
}

extern "C" void kernel_launch(void* const* d_in, const int* in_sizes, int n_in,
                              void* d_out, int out_size, void* d_ws, size_t ws_size,
                              hipStream_t stream) {
    const float* x = (const float*)d_in[0];
    const float* dil = (const float*)d_in[1];
    const float* ero = (const float*)d_in[2];
    float* out = (float*)d_out;

    const size_t outbytes = (size_t)BB * NOUT * sizeof(float);
    int ks = 1;
    if (ws_size >= 8 * outbytes) ks = 8;
    else if (ws_size >= 4 * outbytes) ks = 4;
    else if (ws_size >= 2 * outbytes) ks = 2;

    if (ks > 1) {
        dim3 grid(NOUT / NT, BB / BT, ks);
        trop_main<<<grid, 256, 0, stream>>>(x, dil, ero, (float*)d_ws, ks, FF / ks, 0);
        const int n4 = BB * NOUT / 4;
        trop_combine<<<n4 / 256, 256, 0, stream>>>((const float*)d_ws, out, ks);
    } else {
        dim3 grid(NOUT / NT, BB / BT, 1);
        trop_main<<<grid, 256, 0, stream>>>(x, dil, ero, out, 1, FF, 1);
    }
}